// Round 7
// baseline (213.746 us; speedup 1.0000x reference)
//
#include <hip/hip_runtime.h>

// EnhanceSelfAttention  B=16, N=577, C=768, H=12, d=64.
// R7: 256x256 phase-split GEMM template (8 waves, 4 phases/K-tile, raw
//     s_barrier + counted vmcnt: full next-tile staged at phase0 into the
//     opposite LDS parity, drained only at phase3 -> ~3 phases of latency
//     cover). T2 swizzle + bijective XCD remap (n-fastest). Attention and
//     prep kernels unchanged from R6.

#define BATCH 16
#define SEQ   577
#define CH    768
#define NH    12
#define HD    64
#define MROWS (BATCH*SEQ)   // 9232
#define NRD   2212
#define NP    640           // padded seq (10 x 64)
#define BKT   64            // K per tile
#define NT    (CH/BKT)      // 12 K-tiles

typedef __attribute__((ext_vector_type(8))) short bf16x8;
typedef __attribute__((ext_vector_type(4))) float f32x4;
typedef const __attribute__((address_space(1))) unsigned int* gp_t;
typedef __attribute__((address_space(3))) unsigned int* lp_t;

static __device__ __forceinline__ unsigned short f2bf(float f) {
    unsigned int u = __float_as_uint(f);
    u = (u + 0x7FFFu + ((u >> 16) & 1u)) >> 16;
    return (unsigned short)u;
}
static __device__ __forceinline__ float bf2f(unsigned short b) {
    return __uint_as_float(((unsigned int)b) << 16);
}

// ---------- prep kernels (unchanged) ----------
__global__ __launch_bounds__(256) void conv_bf16_k(
    const float* __restrict__ in, unsigned short* __restrict__ out, int n4)
{
    int i = blockIdx.x * 256 + threadIdx.x;
    if (i < n4) {
        float4 v = ((const float4*)in)[i];
        ushort4 o;
        o.x = f2bf(v.x); o.y = f2bf(v.y); o.z = f2bf(v.z); o.w = f2bf(v.w);
        ((ushort4*)out)[i] = o;
    }
}

__global__ __launch_bounds__(256) void transpose_bf16_k(
    const float* __restrict__ w, unsigned short* __restrict__ wt, int K, int N)
{
    __shared__ float tile[32][33];
    const int n0 = blockIdx.x * 32, k0 = blockIdx.y * 32;
    const int tx = threadIdx.x & 31, ty = threadIdx.x >> 5;
    #pragma unroll
    for (int i = 0; i < 32; i += 8)
        tile[ty + i][tx] = w[(size_t)(k0 + ty + i) * N + n0 + tx];
    __syncthreads();
    #pragma unroll
    for (int i = 0; i < 32; i += 8)
        wt[(size_t)(n0 + ty + i) * K + k0 + tx] = f2bf(tile[tx][ty + i]);
}

__global__ __launch_bounds__(256) void bias_k(
    const float* __restrict__ pos_emb, const int* __restrict__ rel_index,
    unsigned short* __restrict__ biasg)
{
    int i = blockIdx.x * 256 + threadIdx.x;
    if (i < SEQ * SEQ) {
        int idx = rel_index[i];
        #pragma unroll
        for (int h = 0; h < NH; ++h)
            biasg[(size_t)h * SEQ * SEQ + i] = f2bf(pos_emb[h * NRD + idx]);
    }
}

__global__ __launch_bounds__(256) void vtrans_k(
    const unsigned short* __restrict__ v, unsigned short* __restrict__ vt)
{
    __shared__ unsigned short tile[64][68];
    const int bh = blockIdx.y;
    const int n0 = blockIdx.x * 64;
    const int tx = threadIdx.x & 7;
    const int ty = threadIdx.x >> 3;
    const unsigned short* src = v + ((size_t)bh * NP + n0) * HD;
    #pragma unroll
    for (int i = 0; i < 2; ++i) {
        int r = ty + i * 32;
        *(bf16x8*)&tile[r][tx * 8] = *(const bf16x8*)(src + (size_t)r * HD + tx * 8);
    }
    __syncthreads();
    unsigned short* dst = vt + (size_t)bh * HD * NP + n0;
    #pragma unroll
    for (int i = 0; i < 2; ++i) {
        int d = ty + i * 32;
        bf16x8 o;
        #pragma unroll
        for (int e = 0; e < 8; ++e) o[e] = (short)tile[tx * 8 + e][d];
        *(bf16x8*)(dst + (size_t)d * NP + tx * 8) = o;
    }
}

// ---------- 256x256 phase-split bf16 MFMA GEMM ----------
// MODE 0: QKV -> bf16 q/k/v scatter (padded, q pre-scaled).  MODE 1: fp32 out.
// 8 waves: wm = wid>>2 (M half), wn = wid&3 (64-col strip). K = CH = 768.
template<int MODE, int NNB, int NWG>
__global__ __launch_bounds__(512, 2) void gemm256_k(
    const unsigned short* __restrict__ A, const unsigned short* __restrict__ Bt,
    const float* __restrict__ bias, float* __restrict__ fo,
    unsigned short* __restrict__ qo, unsigned short* __restrict__ ko,
    unsigned short* __restrict__ vo)
{
    // [parity][half] 128x64 bf16 half-tiles, row = 128 B (8 granules of 16 B)
    __shared__ unsigned short SA[2 * 2 * 8192];
    __shared__ unsigned short SB[2 * 2 * 8192];

    const int t = threadIdx.x;
    const int wid = t >> 6, lane = t & 63;
    const int wm = wid >> 2, wn = wid & 3;
    const int lr = lane & 15, lg = lane >> 4;

    // bijective XCD remap (m204), n-fastest within chunk
    constexpr int Q = NWG / 8, R = NWG % 8;
    const int raw = blockIdx.x;
    const int xcd = raw & 7, idx = raw >> 3;
    const int wg = (xcd < R ? xcd * (Q + 1) : R * (Q + 1) + (xcd - R) * Q) + idx;
    const int m0 = (wg / NNB) * 256;
    const int n0 = (wg % NNB) * 256;

    // staging coords: 1024 16B units = one 128x64 half-tile; swizzled source
    int srow[2], sgs[2];
    #pragma unroll
    for (int it = 0; it < 2; ++it) {
        int c = t + it * 512;
        srow[it] = c >> 3;
        sgs[it]  = (c & 7) ^ (srow[it] & 7);
    }

    auto stage_all = [&](int par, int k0) {
        #pragma unroll
        for (int h = 0; h < 2; ++h) {
            #pragma unroll
            for (int it = 0; it < 2; ++it) {
                int c = t + it * 512;
                int gm = m0 + h * 128 + srow[it]; gm = gm < MROWS ? gm : MROWS - 1;
                __builtin_amdgcn_global_load_lds(
                    (gp_t)(const void*)(A + (size_t)gm * CH + k0 + sgs[it] * 8),
                    (lp_t)(void*)(SA + (par * 2 + h) * 8192 + c * 8), 16, 0, 0);
            }
        }
        #pragma unroll
        for (int h = 0; h < 2; ++h) {
            #pragma unroll
            for (int it = 0; it < 2; ++it) {
                int c = t + it * 512;
                int gn = n0 + h * 128 + srow[it];
                __builtin_amdgcn_global_load_lds(
                    (gp_t)(const void*)(Bt + (size_t)gn * CH + k0 + sgs[it] * 8),
                    (lp_t)(void*)(SB + (par * 2 + h) * 8192 + c * 8), 16, 0, 0);
            }
        }
    };

    auto loadA = [&](bf16x8* af, int par, int mih, int kh) {
        #pragma unroll
        for (int mi = 0; mi < 4; ++mi) {
            int rA = (mih * 4 + mi) * 16 + lr;
            af[mi] = *(const bf16x8*)(SA + (par * 2 + wm) * 8192 + rA * 64 +
                                      ((((kh << 2) | lg)) ^ (rA & 7)) * 8);
        }
    };
    auto loadB = [&](bf16x8* bfr, int par, int kh) {
        #pragma unroll
        for (int ni = 0; ni < 4; ++ni) {
            int rB = (wn & 1) * 64 + ni * 16 + lr;
            bfr[ni] = *(const bf16x8*)(SB + (par * 2 + (wn >> 1)) * 8192 + rB * 64 +
                                       ((((kh << 2) | lg)) ^ (rB & 7)) * 8);
        }
    };

    f32x4 acc[8][4] = {};

    auto mfmaQ = [&](int mih, bf16x8* af, bf16x8* bfr) {
        #pragma unroll
        for (int mi = 0; mi < 4; ++mi)
            #pragma unroll
            for (int ni = 0; ni < 4; ++ni)
                acc[mih * 4 + mi][ni] = __builtin_amdgcn_mfma_f32_16x16x32_bf16(
                    af[mi], bfr[ni], acc[mih * 4 + mi][ni], 0, 0, 0);
    };

    // prologue: stage tile 0 into parity 0, drain, sync
    stage_all(0, 0);
    asm volatile("s_waitcnt vmcnt(0)" ::: "memory");
    __builtin_amdgcn_s_barrier();
    asm volatile("" ::: "memory");

    for (int tt = 0; tt < NT; ++tt) {
        const int par = tt & 1, nxt = par ^ 1;
        bf16x8 af[4], bfr[4];

        // ---- p0: kh0, mi-half0 (+ stage whole next tile into other parity)
        loadB(bfr, par, 0);
        loadA(af, par, 0, 0);
        if (tt + 1 < NT) stage_all(nxt, (tt + 1) * BKT);
        __builtin_amdgcn_s_barrier();
        asm volatile("s_waitcnt lgkmcnt(0)" ::: "memory");
        __builtin_amdgcn_s_setprio(1); mfmaQ(0, af, bfr); __builtin_amdgcn_s_setprio(0);
        __builtin_amdgcn_s_barrier();
        asm volatile("" ::: "memory");

        // ---- p1: kh0, mi-half1 (B frags reused in regs)
        loadA(af, par, 1, 0);
        __builtin_amdgcn_s_barrier();
        asm volatile("s_waitcnt lgkmcnt(0)" ::: "memory");
        __builtin_amdgcn_s_setprio(1); mfmaQ(1, af, bfr); __builtin_amdgcn_s_setprio(0);
        __builtin_amdgcn_s_barrier();
        asm volatile("" ::: "memory");

        // ---- p2: kh1, mi-half0
        loadB(bfr, par, 1);
        loadA(af, par, 0, 1);
        __builtin_amdgcn_s_barrier();
        asm volatile("s_waitcnt lgkmcnt(0)" ::: "memory");
        __builtin_amdgcn_s_setprio(1); mfmaQ(0, af, bfr); __builtin_amdgcn_s_setprio(0);
        __builtin_amdgcn_s_barrier();
        asm volatile("" ::: "memory");

        // ---- p3: kh1, mi-half1 (+ drain next-tile stage before tile boundary)
        loadA(af, par, 1, 1);
        asm volatile("s_waitcnt vmcnt(0)" ::: "memory");
        __builtin_amdgcn_s_barrier();
        asm volatile("s_waitcnt lgkmcnt(0)" ::: "memory");
        __builtin_amdgcn_s_setprio(1); mfmaQ(1, af, bfr); __builtin_amdgcn_s_setprio(0);
        __builtin_amdgcn_s_barrier();
        asm volatile("" ::: "memory");
    }

    // ---- epilogue ----
    if (MODE == 0) {
        int rb[8][4];
        #pragma unroll
        for (int mi = 0; mi < 8; ++mi) {
            #pragma unroll
            for (int j = 0; j < 4; ++j) {
                int gm = m0 + wm * 128 + mi * 16 + lg * 4 + j;
                int bb = gm / SEQ, ss = gm - bb * SEQ;
                rb[mi][j] = (gm < MROWS) ? (bb * (NH * NP) + ss) : -1;
            }
        }
        const int i3 = n0 / CH;
        unsigned short* dst = (i3 == 0) ? qo : (i3 == 1) ? ko : vo;
        const float scl = (i3 == 0) ? 0.125f : 1.0f;
        const int hh = ((n0 % CH) >> 6) + wn;
        #pragma unroll
        for (int ni = 0; ni < 4; ++ni) {
            const int dd = ni * 16 + lr;
            const float bs = bias[n0 + wn * 64 + dd];
            #pragma unroll
            for (int mi = 0; mi < 8; ++mi) {
                #pragma unroll
                for (int j = 0; j < 4; ++j) {
                    if (rb[mi][j] >= 0)
                        dst[((size_t)(rb[mi][j] + hh * NP)) * HD + dd] =
                            f2bf((acc[mi][ni][j] + bs) * scl);
                }
            }
        }
    } else {
        #pragma unroll
        for (int ni = 0; ni < 4; ++ni) {
            const int gn = n0 + wn * 64 + ni * 16 + lr;
            const float bs = bias[gn];
            #pragma unroll
            for (int mi = 0; mi < 8; ++mi) {
                #pragma unroll
                for (int j = 0; j < 4; ++j) {
                    int gm = m0 + wm * 128 + mi * 16 + lg * 4 + j;
                    if (gm < MROWS)
                        fo[(size_t)gm * CH + gn] = acc[mi][ni][j] + bs;
                }
            }
        }
    }
}

// ---------------- MFMA flash attention (unchanged from R5/R6) ----------------
__global__ __launch_bounds__(256) void attn_mfma_k(
    const unsigned short* __restrict__ qg,
    const unsigned short* __restrict__ kg,
    const unsigned short* __restrict__ vtg,
    const unsigned short* __restrict__ biasg,
    unsigned short* __restrict__ out)
{
    __shared__ unsigned short Qs[64 * 64];
    __shared__ unsigned short Ks[64 * 64];
    __shared__ unsigned short VTs[64 * 64];
    __shared__ unsigned short Ps[64 * 64];

    const int qb = 9 - blockIdx.x;
    const int bh = blockIdx.y;
    const int b = bh / NH, h = bh % NH;
    const int t = threadIdx.x;
    const int wid = t >> 6;
    const int lane = t & 63;
    const int lr = lane & 15, lg = lane >> 4;
    const int q0 = qb * 64;

    const size_t kvbase = (size_t)bh * NP * HD;
    const size_t vtbase = (size_t)bh * HD * NP;

    #pragma unroll
    for (int r = 0; r < 2; ++r) {
        int c = t + r * 256;
        int row = c >> 3, gsrc = (c & 7) ^ (row & 7);
        __builtin_amdgcn_global_load_lds(
            (gp_t)(const void*)(qg + kvbase + (size_t)(q0 + row) * HD + gsrc * 8),
            (lp_t)(void*)(Qs + c * 8), 16, 0, 0);
    }

    f32x4 o_acc[4] = {};
    float m_j[4], l_j[4];
    #pragma unroll
    for (int j = 0; j < 4; ++j) { m_j[j] = -3.0e38f; l_j[j] = 0.f; }

    const int qrow0 = q0 + wid * 16 + lg * 4;

    for (int kb = 0; kb <= qb; ++kb) {
        const int k0 = kb * 64;
        __syncthreads();
        #pragma unroll
        for (int r = 0; r < 2; ++r) {
            int c = t + r * 256;
            int row = c >> 3, gsrc = (c & 7) ^ (row & 7);
            __builtin_amdgcn_global_load_lds(
                (gp_t)(const void*)(kg + kvbase + (size_t)(k0 + row) * HD + gsrc * 8),
                (lp_t)(void*)(Ks + c * 8), 16, 0, 0);
        }
        #pragma unroll
        for (int r = 0; r < 2; ++r) {
            int c = t + r * 256;
            int row = c >> 3, gsrc = (c & 7) ^ (row & 7);
            __builtin_amdgcn_global_load_lds(
                (gp_t)(const void*)(vtg + vtbase + (size_t)row * NP + k0 + gsrc * 8),
                (lp_t)(void*)(VTs + c * 8), 16, 0, 0);
        }
        __syncthreads();

        f32x4 s_acc[4] = {};
        #pragma unroll
        for (int kh = 0; kh < 2; ++kh) {
            const int arow = wid * 16 + lr;
            bf16x8 aq = *(const bf16x8*)(Qs + arow * 64 + ((((kh << 2) | lg)) ^ (arow & 7)) * 8);
            #pragma unroll
            for (int ni = 0; ni < 4; ++ni) {
                const int brow = ni * 16 + lr;
                bf16x8 bk = *(const bf16x8*)(Ks + brow * 64 + ((((kh << 2) | lg)) ^ (brow & 7)) * 8);
                s_acc[ni] = __builtin_amdgcn_mfma_f32_16x16x32_bf16(aq, bk, s_acc[ni], 0, 0, 0);
            }
        }

        float pv[4][4];
        #pragma unroll
        for (int j = 0; j < 4; ++j) {
            const int qrow = qrow0 + j;
            const int qc = qrow < SEQ ? qrow : SEQ - 1;
            float mx = -3.0e38f;
            #pragma unroll
            for (int ni = 0; ni < 4; ++ni) {
                const int kcol = k0 + ni * 16 + lr;
                const int kc = kcol < SEQ ? kcol : SEQ - 1;
                float v = s_acc[ni][j] + bf2f(biasg[((size_t)h * SEQ + qc) * SEQ + kc]);
                if (kcol > qrow) v = -65504.f;
                pv[ni][j] = v;
                mx = fmaxf(mx, v);
            }
            #pragma unroll
            for (int off = 1; off < 16; off <<= 1)
                mx = fmaxf(mx, __shfl_xor(mx, off, 64));
            const float mnew = fmaxf(m_j[j], mx);
            const float f = __expf(m_j[j] - mnew);
            m_j[j] = mnew;
            float sum = 0.f;
            #pragma unroll
            for (int ni = 0; ni < 4; ++ni) {
                float p = __expf(pv[ni][j] - mnew);
                pv[ni][j] = p;
                sum += p;
            }
            #pragma unroll
            for (int off = 1; off < 16; off <<= 1)
                sum += __shfl_xor(sum, off, 64);
            l_j[j] = l_j[j] * f + sum;
            #pragma unroll
            for (int ni = 0; ni < 4; ++ni) o_acc[ni][j] *= f;
        }

        #pragma unroll
        for (int j = 0; j < 4; ++j) {
            const int prow = wid * 16 + lg * 4 + j;
            #pragma unroll
            for (int ni = 0; ni < 4; ++ni) {
                const int col = ni * 16 + lr;
                Ps[prow * 64 + (((col >> 3) ^ (prow & 7)) << 3) + (col & 7)] = f2bf(pv[ni][j]);
            }
        }
        __syncthreads();

        #pragma unroll
        for (int kh = 0; kh < 2; ++kh) {
            const int arow = wid * 16 + lr;
            bf16x8 pa = *(const bf16x8*)(Ps + arow * 64 + ((((kh << 2) | lg)) ^ (arow & 7)) * 8);
            #pragma unroll
            for (int ni = 0; ni < 4; ++ni) {
                const int brow = ni * 16 + lr;
                bf16x8 bv = *(const bf16x8*)(VTs + brow * 64 + ((((kh << 2) | lg)) ^ (brow & 7)) * 8);
                o_acc[ni] = __builtin_amdgcn_mfma_f32_16x16x32_bf16(pa, bv, o_acc[ni], 0, 0, 0);
            }
        }
    }

    #pragma unroll
    for (int j = 0; j < 4; ++j) {
        const int qrow = qrow0 + j;
        if (qrow < SEQ) {
            const float inv = 1.0f / l_j[j];
            const size_t base = ((size_t)b * SEQ + qrow) * CH + h * HD;
            #pragma unroll
            for (int ni = 0; ni < 4; ++ni)
                out[base + ni * 16 + lr] = f2bf(o_acc[ni][j] * inv);
        }
    }
}

extern "C" void kernel_launch(void* const* d_in, const int* in_sizes, int n_in,
                              void* d_out, int out_size, void* d_ws, size_t ws_size,
                              hipStream_t stream) {
    const float* x        = (const float*)d_in[0];
    const float* qkv_w    = (const float*)d_in[1];
    const float* qkv_b    = (const float*)d_in[2];
    const float* pos_emb  = (const float*)d_in[3];
    const float* out_w    = (const float*)d_in[4];
    const float* out_b    = (const float*)d_in[5];
    const int*   rel_idx  = (const int*)d_in[6];
    float* out = (float*)d_out;

    const size_t QP = (size_t)BATCH * NH * NP * HD;
    unsigned short* qp  = (unsigned short*)d_ws;
    unsigned short* kp  = qp + QP;
    unsigned short* vp  = kp + QP;
    unsigned short* vt  = vp + QP;
    unsigned short* xb  = vt + QP;                        // x bf16; attn out aliases
    unsigned short* qwt = xb + (size_t)MROWS * CH;
    unsigned short* owt = qwt + (size_t)(3 * CH) * CH;
    unsigned short* bg  = owt + (size_t)CH * CH;

    conv_bf16_k<<<(MROWS * CH / 4 + 255) / 256, 256, 0, stream>>>(x, xb, MROWS * CH / 4);
    transpose_bf16_k<<<dim3(3 * CH / 32, CH / 32), 256, 0, stream>>>(qkv_w, qwt, CH, 3 * CH);
    transpose_bf16_k<<<dim3(CH / 32, CH / 32), 256, 0, stream>>>(out_w, owt, CH, CH);
    bias_k<<<(SEQ * SEQ + 255) / 256, 256, 0, stream>>>(pos_emb, rel_idx, bg);

    // K1: qkv  (M=9232 -> 37 m-blocks, N=2304 -> 9 n-blocks, NWG=333)
    gemm256_k<0, 9, 333><<<333, 512, 0, stream>>>(xb, qwt, qkv_b, nullptr, qp, kp, vp);

    vtrans_k<<<dim3(NP / 64, BATCH * NH), 256, 0, stream>>>(vp, vt);

    attn_mfma_k<<<dim3(10, BATCH * NH), 256, 0, stream>>>(qp, kp, vt, bg, xb);

    // K3: proj (N=768 -> 3 n-blocks, NWG=111)
    gemm256_k<1, 3, 111><<<111, 512, 0, stream>>>(xb, owt, out_b, out, nullptr, nullptr, nullptr);
}

// Round 8
// 204.359 us; speedup vs baseline: 1.0459x; 1.0459x over previous
//
#include <hip/hip_runtime.h>

// EnhanceSelfAttention  B=16, N=577, C=768, H=12, d=64.
// R8: revert to 128^2 GEMM geometry (2 blocks/CU), replace 2-phase dbuf with
//     ring-4 BK=32 counted-vmcnt pipeline: stage(t+3) each iter, compute(t),
//     s_waitcnt vmcnt(8) (t+2,t+3 stay in flight), raw s_barrier. Never a
//     full drain in steady state. Attention + prep unchanged from R6.

#define BATCH 16
#define SEQ   577
#define CH    768
#define NH    12
#define HD    64
#define MROWS (BATCH*SEQ)   // 9232
#define NRD   2212
#define NP    640           // padded seq (10 x 64)

#define BM 128
#define BN 128

typedef __attribute__((ext_vector_type(8))) short bf16x8;
typedef __attribute__((ext_vector_type(4))) float f32x4;
typedef const __attribute__((address_space(1))) unsigned int* gp_t;
typedef __attribute__((address_space(3))) unsigned int* lp_t;

static __device__ __forceinline__ unsigned short f2bf(float f) {
    unsigned int u = __float_as_uint(f);
    u = (u + 0x7FFFu + ((u >> 16) & 1u)) >> 16;
    return (unsigned short)u;
}
static __device__ __forceinline__ float bf2f(unsigned short b) {
    return __uint_as_float(((unsigned int)b) << 16);
}

// ---------- prep kernels (unchanged) ----------
__global__ __launch_bounds__(256) void conv_bf16_k(
    const float* __restrict__ in, unsigned short* __restrict__ out, int n4)
{
    int i = blockIdx.x * 256 + threadIdx.x;
    if (i < n4) {
        float4 v = ((const float4*)in)[i];
        ushort4 o;
        o.x = f2bf(v.x); o.y = f2bf(v.y); o.z = f2bf(v.z); o.w = f2bf(v.w);
        ((ushort4*)out)[i] = o;
    }
}

__global__ __launch_bounds__(256) void transpose_bf16_k(
    const float* __restrict__ w, unsigned short* __restrict__ wt, int K, int N)
{
    __shared__ float tile[32][33];
    const int n0 = blockIdx.x * 32, k0 = blockIdx.y * 32;
    const int tx = threadIdx.x & 31, ty = threadIdx.x >> 5;
    #pragma unroll
    for (int i = 0; i < 32; i += 8)
        tile[ty + i][tx] = w[(size_t)(k0 + ty + i) * N + n0 + tx];
    __syncthreads();
    #pragma unroll
    for (int i = 0; i < 32; i += 8)
        wt[(size_t)(n0 + ty + i) * K + k0 + tx] = f2bf(tile[tx][ty + i]);
}

__global__ __launch_bounds__(256) void bias_k(
    const float* __restrict__ pos_emb, const int* __restrict__ rel_index,
    unsigned short* __restrict__ biasg)
{
    int i = blockIdx.x * 256 + threadIdx.x;
    if (i < SEQ * SEQ) {
        int idx = rel_index[i];
        #pragma unroll
        for (int h = 0; h < NH; ++h)
            biasg[(size_t)h * SEQ * SEQ + i] = f2bf(pos_emb[h * NRD + idx]);
    }
}

__global__ __launch_bounds__(256) void vtrans_k(
    const unsigned short* __restrict__ v, unsigned short* __restrict__ vt)
{
    __shared__ unsigned short tile[64][68];
    const int bh = blockIdx.y;
    const int n0 = blockIdx.x * 64;
    const int tx = threadIdx.x & 7;
    const int ty = threadIdx.x >> 3;
    const unsigned short* src = v + ((size_t)bh * NP + n0) * HD;
    #pragma unroll
    for (int i = 0; i < 2; ++i) {
        int r = ty + i * 32;
        *(bf16x8*)&tile[r][tx * 8] = *(const bf16x8*)(src + (size_t)r * HD + tx * 8);
    }
    __syncthreads();
    unsigned short* dst = vt + (size_t)bh * HD * NP + n0;
    #pragma unroll
    for (int i = 0; i < 2; ++i) {
        int d = ty + i * 32;
        bf16x8 o;
        #pragma unroll
        for (int e = 0; e < 8; ++e) o[e] = (short)tile[tx * 8 + e][d];
        *(bf16x8*)(dst + (size_t)d * NP + tx * 8) = o;
    }
}

// ---------- bf16 MFMA GEMM: 128^2 tile, ring-4 BK=32 counted-vmcnt ----------
// MODE 0: QKV -> bf16 q/k/v scatter (padded, q pre-scaled). MODE 1: fp32 out.
template<int MODE>
__global__ __launch_bounds__(256) void gemm_bf16_k(
    const unsigned short* __restrict__ A, const unsigned short* __restrict__ Bt,
    const float* __restrict__ bias, float* __restrict__ fo,
    unsigned short* __restrict__ qo, unsigned short* __restrict__ ko,
    unsigned short* __restrict__ vo)
{
    constexpr int BK2 = 32;
    constexpr int NT2 = CH / BK2;   // 24 K-tiles
    __shared__ unsigned short SA[4][BM * BK2];   // 4 x 8 KB
    __shared__ unsigned short SB[4][BN * BK2];   // 4 x 8 KB

    const int t = threadIdx.x;
    const int wid = t >> 6, lane = t & 63;
    const int m0 = blockIdx.y * BM;
    const int n0 = blockIdx.x * BN;
    const int wr = wid >> 1, wc = wid & 1;
    const int lr = lane & 15, lg = lane >> 4;

    // staging coords: 512 units of 16B per 128x32 tile; 2 units/thread.
    // swizzle: source granule = g ^ (row&3)  (read applies the same XOR)
    int srow[2], sgs[2], gmA[2];
    #pragma unroll
    for (int it = 0; it < 2; ++it) {
        int u = t + it * 256;
        srow[it] = u >> 2;
        sgs[it]  = (u & 3) ^ (srow[it] & 3);
        int gm = m0 + srow[it];
        gmA[it] = gm < MROWS ? gm : MROWS - 1;
    }

    auto stage = [&](int buf, int k0) {
        #pragma unroll
        for (int it = 0; it < 2; ++it) {
            __builtin_amdgcn_global_load_lds(
                (gp_t)(const void*)(A + (size_t)gmA[it] * CH + k0 + sgs[it] * 8),
                (lp_t)(void*)(&SA[buf][(t + it * 256) * 8]), 16, 0, 0);
        }
        #pragma unroll
        for (int it = 0; it < 2; ++it) {
            __builtin_amdgcn_global_load_lds(
                (gp_t)(const void*)(Bt + (size_t)(n0 + srow[it]) * CH + k0 + sgs[it] * 8),
                (lp_t)(void*)(&SB[buf][(t + it * 256) * 8]), 16, 0, 0);
        }
    };

    f32x4 acc[4][4] = {};

    // prologue: stage tiles 0..2, ensure tile 0 landed (t1,t2 stay in flight)
    stage(0, 0); stage(1, BK2); stage(2, 2 * BK2);
    asm volatile("s_waitcnt vmcnt(8)" ::: "memory");
    __builtin_amdgcn_s_barrier();
    asm volatile("" ::: "memory");

    for (int tt = 0; tt < NT2; ++tt) {
        if (tt + 3 < NT2) stage((tt + 3) & 3, (tt + 3) * BK2);

        const unsigned short* Abuf = SA[tt & 3];
        const unsigned short* Bbuf = SB[tt & 3];
        bf16x8 af[4], bfr[4];
        #pragma unroll
        for (int mi = 0; mi < 4; ++mi) {
            int rA = wr * 64 + mi * 16 + lr;
            af[mi] = *(const bf16x8*)(Abuf + rA * BK2 + ((lg ^ (rA & 3)) * 8));
        }
        #pragma unroll
        for (int ni = 0; ni < 4; ++ni) {
            int rB = wc * 64 + ni * 16 + lr;
            bfr[ni] = *(const bf16x8*)(Bbuf + rB * BK2 + ((lg ^ (rB & 3)) * 8));
        }
        __builtin_amdgcn_s_setprio(1);
        #pragma unroll
        for (int mi = 0; mi < 4; ++mi)
            #pragma unroll
            for (int ni = 0; ni < 4; ++ni)
                acc[mi][ni] = __builtin_amdgcn_mfma_f32_16x16x32_bf16(
                    af[mi], bfr[ni], acc[mi][ni], 0, 0, 0);
        __builtin_amdgcn_s_setprio(0);

        // counted waits: next tile must be resident; deeper tiles stay in flight
        if (tt <= NT2 - 4)      { asm volatile("s_waitcnt vmcnt(8)" ::: "memory"); }
        else if (tt == NT2 - 3) { asm volatile("s_waitcnt vmcnt(4)" ::: "memory"); }
        else if (tt == NT2 - 2) { asm volatile("s_waitcnt vmcnt(0)" ::: "memory"); }
        __builtin_amdgcn_s_barrier();
        asm volatile("" ::: "memory");
    }

    // ---- epilogue (same as R6) ----
    if (MODE == 0) {
        int rbase[16];
        #pragma unroll
        for (int mi = 0; mi < 4; ++mi) {
            #pragma unroll
            for (int j = 0; j < 4; ++j) {
                int gm = m0 + wr * 64 + mi * 16 + lg * 4 + j;
                int bb = gm / SEQ, ss = gm - bb * SEQ;
                rbase[mi * 4 + j] = (gm < MROWS) ? (bb * NH * NP + ss) : -1;
            }
        }
        #pragma unroll
        for (int ni = 0; ni < 4; ++ni) {
            const int gn = n0 + wc * 64 + ni * 16 + lr;
            const float bs = bias[gn];
            const int i3 = gn / CH;
            const int hh = (gn % CH) / HD;
            const int dd = gn % HD;
            unsigned short* dst = (i3 == 0) ? qo : (i3 == 1) ? ko : vo;
            const float scl = (i3 == 0) ? 0.125f : 1.0f;
            #pragma unroll
            for (int mi = 0; mi < 4; ++mi) {
                #pragma unroll
                for (int j = 0; j < 4; ++j) {
                    int rb = rbase[mi * 4 + j];
                    if (rb >= 0)
                        dst[((size_t)rb + (size_t)hh * NP) * HD + dd] =
                            f2bf((acc[mi][ni][j] + bs) * scl);
                }
            }
        }
    } else {
        #pragma unroll
        for (int ni = 0; ni < 4; ++ni) {
            const int gn = n0 + wc * 64 + ni * 16 + lr;
            const float bs = bias[gn];
            #pragma unroll
            for (int mi = 0; mi < 4; ++mi) {
                #pragma unroll
                for (int j = 0; j < 4; ++j) {
                    int gm = m0 + wr * 64 + mi * 16 + lg * 4 + j;
                    if (gm < MROWS)
                        fo[(size_t)gm * CH + gn] = acc[mi][ni][j] + bs;
                }
            }
        }
    }
}

// ---------------- MFMA flash attention (unchanged from R5/R6) ----------------
__global__ __launch_bounds__(256) void attn_mfma_k(
    const unsigned short* __restrict__ qg,
    const unsigned short* __restrict__ kg,
    const unsigned short* __restrict__ vtg,
    const unsigned short* __restrict__ biasg,
    unsigned short* __restrict__ out)
{
    __shared__ unsigned short Qs[64 * 64];
    __shared__ unsigned short Ks[64 * 64];
    __shared__ unsigned short VTs[64 * 64];
    __shared__ unsigned short Ps[64 * 64];

    const int qb = 9 - blockIdx.x;
    const int bh = blockIdx.y;
    const int b = bh / NH, h = bh % NH;
    const int t = threadIdx.x;
    const int wid = t >> 6;
    const int lane = t & 63;
    const int lr = lane & 15, lg = lane >> 4;
    const int q0 = qb * 64;

    const size_t kvbase = (size_t)bh * NP * HD;
    const size_t vtbase = (size_t)bh * HD * NP;

    #pragma unroll
    for (int r = 0; r < 2; ++r) {
        int c = t + r * 256;
        int row = c >> 3, gsrc = (c & 7) ^ (row & 7);
        __builtin_amdgcn_global_load_lds(
            (gp_t)(const void*)(qg + kvbase + (size_t)(q0 + row) * HD + gsrc * 8),
            (lp_t)(void*)(Qs + c * 8), 16, 0, 0);
    }

    f32x4 o_acc[4] = {};
    float m_j[4], l_j[4];
    #pragma unroll
    for (int j = 0; j < 4; ++j) { m_j[j] = -3.0e38f; l_j[j] = 0.f; }

    const int qrow0 = q0 + wid * 16 + lg * 4;

    for (int kb = 0; kb <= qb; ++kb) {
        const int k0 = kb * 64;
        __syncthreads();
        #pragma unroll
        for (int r = 0; r < 2; ++r) {
            int c = t + r * 256;
            int row = c >> 3, gsrc = (c & 7) ^ (row & 7);
            __builtin_amdgcn_global_load_lds(
                (gp_t)(const void*)(kg + kvbase + (size_t)(k0 + row) * HD + gsrc * 8),
                (lp_t)(void*)(Ks + c * 8), 16, 0, 0);
        }
        #pragma unroll
        for (int r = 0; r < 2; ++r) {
            int c = t + r * 256;
            int row = c >> 3, gsrc = (c & 7) ^ (row & 7);
            __builtin_amdgcn_global_load_lds(
                (gp_t)(const void*)(vtg + vtbase + (size_t)row * NP + k0 + gsrc * 8),
                (lp_t)(void*)(VTs + c * 8), 16, 0, 0);
        }
        __syncthreads();

        f32x4 s_acc[4] = {};
        #pragma unroll
        for (int kh = 0; kh < 2; ++kh) {
            const int arow = wid * 16 + lr;
            bf16x8 aq = *(const bf16x8*)(Qs + arow * 64 + ((((kh << 2) | lg)) ^ (arow & 7)) * 8);
            #pragma unroll
            for (int ni = 0; ni < 4; ++ni) {
                const int brow = ni * 16 + lr;
                bf16x8 bk = *(const bf16x8*)(Ks + brow * 64 + ((((kh << 2) | lg)) ^ (brow & 7)) * 8);
                s_acc[ni] = __builtin_amdgcn_mfma_f32_16x16x32_bf16(aq, bk, s_acc[ni], 0, 0, 0);
            }
        }

        float pv[4][4];
        #pragma unroll
        for (int j = 0; j < 4; ++j) {
            const int qrow = qrow0 + j;
            const int qc = qrow < SEQ ? qrow : SEQ - 1;
            float mx = -3.0e38f;
            #pragma unroll
            for (int ni = 0; ni < 4; ++ni) {
                const int kcol = k0 + ni * 16 + lr;
                const int kc = kcol < SEQ ? kcol : SEQ - 1;
                float v = s_acc[ni][j] + bf2f(biasg[((size_t)h * SEQ + qc) * SEQ + kc]);
                if (kcol > qrow) v = -65504.f;
                pv[ni][j] = v;
                mx = fmaxf(mx, v);
            }
            #pragma unroll
            for (int off = 1; off < 16; off <<= 1)
                mx = fmaxf(mx, __shfl_xor(mx, off, 64));
            const float mnew = fmaxf(m_j[j], mx);
            const float f = __expf(m_j[j] - mnew);
            m_j[j] = mnew;
            float sum = 0.f;
            #pragma unroll
            for (int ni = 0; ni < 4; ++ni) {
                float p = __expf(pv[ni][j] - mnew);
                pv[ni][j] = p;
                sum += p;
            }
            #pragma unroll
            for (int off = 1; off < 16; off <<= 1)
                sum += __shfl_xor(sum, off, 64);
            l_j[j] = l_j[j] * f + sum;
            #pragma unroll
            for (int ni = 0; ni < 4; ++ni) o_acc[ni][j] *= f;
        }

        #pragma unroll
        for (int j = 0; j < 4; ++j) {
            const int prow = wid * 16 + lg * 4 + j;
            #pragma unroll
            for (int ni = 0; ni < 4; ++ni) {
                const int col = ni * 16 + lr;
                Ps[prow * 64 + (((col >> 3) ^ (prow & 7)) << 3) + (col & 7)] = f2bf(pv[ni][j]);
            }
        }
        __syncthreads();

        #pragma unroll
        for (int kh = 0; kh < 2; ++kh) {
            const int arow = wid * 16 + lr;
            bf16x8 pa = *(const bf16x8*)(Ps + arow * 64 + ((((kh << 2) | lg)) ^ (arow & 7)) * 8);
            #pragma unroll
            for (int ni = 0; ni < 4; ++ni) {
                const int brow = ni * 16 + lr;
                bf16x8 bv = *(const bf16x8*)(VTs + brow * 64 + ((((kh << 2) | lg)) ^ (brow & 7)) * 8);
                o_acc[ni] = __builtin_amdgcn_mfma_f32_16x16x32_bf16(pa, bv, o_acc[ni], 0, 0, 0);
            }
        }
    }

    #pragma unroll
    for (int j = 0; j < 4; ++j) {
        const int qrow = qrow0 + j;
        if (qrow < SEQ) {
            const float inv = 1.0f / l_j[j];
            const size_t base = ((size_t)b * SEQ + qrow) * CH + h * HD;
            #pragma unroll
            for (int ni = 0; ni < 4; ++ni)
                out[base + ni * 16 + lr] = f2bf(o_acc[ni][j] * inv);
        }
    }
}

extern "C" void kernel_launch(void* const* d_in, const int* in_sizes, int n_in,
                              void* d_out, int out_size, void* d_ws, size_t ws_size,
                              hipStream_t stream) {
    const float* x        = (const float*)d_in[0];
    const float* qkv_w    = (const float*)d_in[1];
    const float* qkv_b    = (const float*)d_in[2];
    const float* pos_emb  = (const float*)d_in[3];
    const float* out_w    = (const float*)d_in[4];
    const float* out_b    = (const float*)d_in[5];
    const int*   rel_idx  = (const int*)d_in[6];
    float* out = (float*)d_out;

    const size_t QP = (size_t)BATCH * NH * NP * HD;
    unsigned short* qp  = (unsigned short*)d_ws;
    unsigned short* kp  = qp + QP;
    unsigned short* vp  = kp + QP;
    unsigned short* vt  = vp + QP;
    unsigned short* xb  = vt + QP;                        // x bf16; attn out aliases
    unsigned short* qwt = xb + (size_t)MROWS * CH;
    unsigned short* owt = qwt + (size_t)(3 * CH) * CH;
    unsigned short* bg  = owt + (size_t)CH * CH;

    conv_bf16_k<<<(MROWS * CH / 4 + 255) / 256, 256, 0, stream>>>(x, xb, MROWS * CH / 4);
    transpose_bf16_k<<<dim3(3 * CH / 32, CH / 32), 256, 0, stream>>>(qkv_w, qwt, CH, 3 * CH);
    transpose_bf16_k<<<dim3(CH / 32, CH / 32), 256, 0, stream>>>(out_w, owt, CH, CH);
    bias_k<<<(SEQ * SEQ + 255) / 256, 256, 0, stream>>>(pos_emb, rel_idx, bg);

    // K1: qkv
    gemm_bf16_k<0><<<dim3(3 * CH / BN, (MROWS + BM - 1) / BM), 256, 0, stream>>>(
        xb, qwt, qkv_b, nullptr, qp, kp, vp);

    vtrans_k<<<dim3(NP / 64, BATCH * NH), 256, 0, stream>>>(vp, vt);

    attn_mfma_k<<<dim3(10, BATCH * NH), 256, 0, stream>>>(qp, kp, vt, bg, xb);

    // K3: projection
    gemm_bf16_k<1><<<dim3(CH / BN, (MROWS + BM - 1) / BM), 256, 0, stream>>>(
        xb, owt, out_b, out, nullptr, nullptr, nullptr);
}